// Round 2
// baseline (339.217 us; speedup 1.0000x reference)
//
#include <hip/hip_runtime.h>

// RoPE2D cos/sin table generator — float32.
// Output: [cos_2d (rows*dim)] ++ [sin_2d (rows*dim)], rows = H*W, dim = dimx+dimy.
// Row p = y*W + x. Channel c:
//   c in [0, dimx):   val = trig(x * ifx[c mod (dimx/2)])
//   c in [dimx, dim): val = trig(y * ify[(c-dimx) mod (dimy/2)])
//
// v3: pure streaming-store structure (fill-kernel shaped). Grid-stride with
// 2048 blocks x 256 threads; one iteration = one lane-contiguous dwordx4
// store (1 KB per wave per store). All row/channel bookkeeping is either
// provably loop-invariant (ch, freq vector: stride*4 % 128 == 0) or a few
// shifts/ands per iteration. is_sin is wave-uniform -> uniform branch runs
// only v_sin OR v_cos (4 trans per 16 B stored).
// Compute roofline: ~12 VALU + 4 trans per 16 B -> ~8 us; store roofline:
// 268 MB / 6.3 TB/s ~ 43 us. Kernel should sit at the write roofline.

typedef __attribute__((ext_vector_type(4))) float float4v;

// Fast path: dimx = dimy = 64 (dim = 128, half-tables of 32 floats).
__global__ __launch_bounds__(256) void rope2d_stream(
    const float* __restrict__ ifx,
    const float* __restrict__ ify,
    const int* __restrict__ wptr,
    float* __restrict__ out,
    int rows)
{
    const int total4 = rows << 6;                  // 2*rows*128/4 store-quads
    const int stride = gridDim.x * blockDim.x;     // multiple of 64 by construction
    const int idx0 = blockIdx.x * blockDim.x + threadIdx.x;
    if (idx0 >= total4) return;

    const int half = rows << 7;                    // rows*128 floats (cos half size)
    const int W = *wptr;                           // one 4B load, loop-invariant
    const bool pw2 = (W & (W - 1)) == 0;
    const int wm1 = W - 1;
    const int wsh = __ffs(W) - 1;

    // stride*4 % 128 == 0  =>  channel of this thread's quad never changes.
    const int ch = (idx0 << 2) & 127;              // first channel of the 4 (4-aligned)
    const bool use_x = ch < 64;                    // x-quadrant vs y-quadrant, invariant
    const float4v fr =
        *reinterpret_cast<const float4v*>((use_x ? ifx : ify) + (ch & 31)); // 16B, L1

    for (int idx = idx0; idx < total4; idx += stride) {
        const int e = idx << 2;                    // element offset in flat output
        const bool is_sin = e >= half;             // wave-uniform
        const int e2 = is_sin ? e - half : e;
        const int p = e2 >> 7;                     // row = y*W + x

        int xw, yh;
        if (pw2) { xw = p & wm1; yh = p >> wsh; }
        else     { xw = p % W;   yh = p / W;    }
        const float pos = (float)(use_x ? xw : yh);

        float4v v;
        if (is_sin) {                              // uniform branch: 4 trans only
#pragma unroll
            for (int i = 0; i < 4; ++i) v[i] = __sinf(pos * fr[i]);
        } else {
#pragma unroll
            for (int i = 0; i < 4; ++i) v[i] = __cosf(pos * fr[i]);
        }

        *reinterpret_cast<float4v*>(out + e) = v;  // dense dwordx4, lanes contiguous
    }
}

// Generic path: arbitrary dimx/dimy (scalar per element, grid-stride).
__global__ __launch_bounds__(256) void rope2d_generic(
    const float* __restrict__ ifx,
    const float* __restrict__ ify,
    const int* __restrict__ wptr,
    float* __restrict__ out,
    int rows, int dimx, int dimy)
{
    const int dim = dimx + dimy;
    const long long total = 2LL * rows * dim;
    const long long stride = (long long)gridDim.x * blockDim.x;
    const long long halfo = (long long)rows * dim;
    const int W = *wptr;

    for (long long e = (long long)blockIdx.x * blockDim.x + threadIdx.x;
         e < total; e += stride) {
        const bool is_sin = e >= halfo;
        const long long e2 = is_sin ? e - halfo : e;
        const int p  = (int)(e2 / dim);
        const int ch = (int)(e2 % dim);

        const int xw = p % W, yh = p / W;

        float pos, f;
        if (ch < dimx) { pos = (float)xw; f = ifx[ch % (dimx >> 1)]; }
        else           { pos = (float)yh; f = ify[(ch - dimx) % (dimy >> 1)]; }
        const float ang = pos * f;
        out[e] = is_sin ? __sinf(ang) : __cosf(ang);
    }
}

extern "C" void kernel_launch(void* const* d_in, const int* in_sizes, int n_in,
                              void* d_out, int out_size, void* d_ws, size_t ws_size,
                              hipStream_t stream) {
    // inputs: [0]=x (f32, dtype-only), [1]=inv_freq_x (f32), [2]=inv_freq_y (f32),
    //         [3]=height (int32), [4]=width (int32)
    const float* ifx = (const float*)d_in[1];
    const float* ify = (const float*)d_in[2];
    const int* wptr  = (const int*)d_in[4];
    float* out = (float*)d_out;

    const int dimx = 2 * in_sizes[1];      // 64
    const int dimy = 2 * in_sizes[2];      // 64
    const int dim  = dimx + dimy;          // 128
    const int rows = in_sizes[0] / dim;    // H*W = 262144

    const int block = 256;

    if (dimx == 64 && dimy == 64) {
        const int total4 = rows << 6;                       // 16,777,216 quads
        int grid = 2048;                                    // 8 blocks/CU, grid-stride
        const int maxg = (total4 + block - 1) / block;
        if (grid > maxg) grid = maxg;
        rope2d_stream<<<grid, block, 0, stream>>>(ifx, ify, wptr, out, rows);
    } else {
        const long long total = 2LL * rows * dim;
        long long maxg = (total + block - 1) / block;
        int grid = maxg < 2048 ? (int)maxg : 2048;
        rope2d_generic<<<grid, block, 0, stream>>>(ifx, ify, wptr, out, rows, dimx, dimy);
    }
}

// Round 3
// 324.919 us; speedup vs baseline: 1.0440x; 1.0440x over previous
//
#include <hip/hip_runtime.h>

// RoPE2D cos/sin table generator — float32.
// Output: [cos_2d (rows*dim)] ++ [sin_2d (rows*dim)], rows = H*W, dim = dimx+dimy.
// Row p = y*W + x. Channel c:
//   c in [0, dimx):   val = trig(x * ifx[c mod (dimx/2)])
//   c in [dimx, dim): val = trig(y * ify[(c-dimx) mod (dimy/2)])
//
// v4: back to the proven one-thread-per-quad dense mapping (r0 structure),
// but cos/sin split into two template launches. Each thread: ~15 VALU,
// exactly 4 trans (v_sin OR v_cos — no predicated both-sides), one
// lane-contiguous dwordx4 store. Aggregate compute ~8 us vs 43 us store
// roofline (268 MB @ 6.3 TB/s) -> store-bound.

typedef __attribute__((ext_vector_type(4))) float float4v;

// Fast path: dimx = dimy = 64 (dim = 128, half-tables of 32 floats).
// Covers HALF the output (cos half or sin half): rows*128 floats = rows*32 quads.
template <bool IS_SIN>
__global__ __launch_bounds__(256) void rope2d_half(
    const float* __restrict__ ifx,
    const float* __restrict__ ify,
    const int* __restrict__ wptr,
    float* __restrict__ outh,        // base of this half
    int rows)
{
    const int idx = blockIdx.x * blockDim.x + threadIdx.x;
    const int total4 = rows << 5;            // rows*128/4 quads in this half
    if (idx >= total4) return;

    const int e = idx << 2;                  // element offset within the half
    const int p  = idx >> 5;                 // row (e >> 7)
    const int ch = e & 127;                  // first channel of the 4 (4-aligned)

    const int W = *wptr;                     // uniform 4B load, L1/broadcast
    int xw, yh;
    if ((W & (W - 1)) == 0) {
        const int s = __ffs(W) - 1;
        xw = p & (W - 1);
        yh = p >> s;
    } else {
        xw = p % W;
        yh = p / W;
    }

    // quadrants: ch [0,64) -> x-table, [64,128) -> y-table; fidx = ch & 31
    const bool use_x = ch < 64;
    const float pos = use_x ? (float)xw : (float)yh;
    const float* tab = use_x ? ifx : ify;
    const float4v fr = *reinterpret_cast<const float4v*>(tab + (ch & 31)); // 16B, L1

    float4v v;
#pragma unroll
    for (int i = 0; i < 4; ++i) {
        const float f = pos * fr[i];
        v[i] = IS_SIN ? __sinf(f) : __cosf(f);   // compile-time: exactly 4 trans
    }

    *reinterpret_cast<float4v*>(outh + e) = v;   // dense dwordx4, lanes contiguous
}

// Generic path: arbitrary dimx/dimy (scalar per element, one-shot).
__global__ __launch_bounds__(256) void rope2d_generic(
    const float* __restrict__ ifx,
    const float* __restrict__ ify,
    const int* __restrict__ wptr,
    float* __restrict__ out,
    int rows, int dimx, int dimy)
{
    const int dim = dimx + dimy;
    const long long total = 2LL * rows * dim;
    const long long e = (long long)(blockIdx.x * blockDim.x + threadIdx.x)
                      + (long long)blockIdx.y * (1LL << 30);
    if (e >= total) return;

    const long long halfo = (long long)rows * dim;
    const bool is_sin = e >= halfo;
    const long long e2 = is_sin ? e - halfo : e;
    const int p  = (int)(e2 / dim);
    const int ch = (int)(e2 % dim);

    const int W = *wptr;
    const int xw = p % W, yh = p / W;

    float pos, f;
    if (ch < dimx) { pos = (float)xw; f = ifx[ch % (dimx >> 1)]; }
    else           { pos = (float)yh; f = ify[(ch - dimx) % (dimy >> 1)]; }
    const float ang = pos * f;
    out[e] = is_sin ? __sinf(ang) : __cosf(ang);
}

extern "C" void kernel_launch(void* const* d_in, const int* in_sizes, int n_in,
                              void* d_out, int out_size, void* d_ws, size_t ws_size,
                              hipStream_t stream) {
    // inputs: [0]=x (f32, dtype-only), [1]=inv_freq_x (f32), [2]=inv_freq_y (f32),
    //         [3]=height (int32), [4]=width (int32)
    const float* ifx = (const float*)d_in[1];
    const float* ify = (const float*)d_in[2];
    const int* wptr  = (const int*)d_in[4];
    float* out = (float*)d_out;

    const int dimx = 2 * in_sizes[1];      // 64
    const int dimy = 2 * in_sizes[2];      // 64
    const int dim  = dimx + dimy;          // 128
    const int rows = in_sizes[0] / dim;    // H*W = 262144

    const int block = 256;

    if (dimx == 64 && dimy == 64) {
        const int total4 = rows << 5;                      // quads per half: 8,388,608
        const int grid = (total4 + block - 1) / block;     // 32,768 blocks per half
        float* out_sin = out + ((size_t)rows << 7);        // + rows*128
        rope2d_half<false><<<grid, block, 0, stream>>>(ifx, ify, wptr, out, rows);
        rope2d_half<true ><<<grid, block, 0, stream>>>(ifx, ify, wptr, out_sin, rows);
    } else {
        const long long total = 2LL * rows * dim;
        const long long grid = (total + block - 1) / block;
        rope2d_generic<<<(int)grid, block, 0, stream>>>(ifx, ify, wptr, out,
                                                        rows, dimx, dimy);
    }
}